// Round 5
// baseline (356.029 us; speedup 1.0000x reference)
//
#include <hip/hip_runtime.h>
#include <hip/hip_bf16.h>
#include <math.h>

// GATEncoder round 5.
// - gat_gather4: phase A computes edge softmax numerators lane-parallel (1 lane
//   = 1 edge, all heads) into per-wave LDS; phase B inner loop is only
//   {ds_read2(p,s), h-load, 2 unpack, 2 fma}. Denom = lane-local + one final
//   butterfly. Round-4 gather was VALU-bound (80%) on 64x-replicated exp/select.
// - gemm_att: attention logits (a_src/a_dst) computed in the GEMM epilogue via
//   LDS reduction; f32 h buffer and both att_kernel dispatches deleted.

#define NEG_SLOPE 0.2f

// ---------------- CSR build ----------------
__global__ void deg_hist(const int* __restrict__ ei, int* __restrict__ deg, int E) {
    int e = blockIdx.x * blockDim.x + threadIdx.x;
    if (e < E) atomicAdd(&deg[ei[E + e]], 1);
}

__global__ __launch_bounds__(256) void scan_part(const int* __restrict__ deg,
                                                 int* __restrict__ bsum, int n) {
    const int t = threadIdx.x;
    const int i0 = blockIdx.x * 1024 + t * 4;
    int s = 0;
#pragma unroll
    for (int k = 0; k < 4; ++k) { int i = i0 + k; if (i < n) s += deg[i] + 1; }
#pragma unroll
    for (int o = 1; o < 64; o <<= 1) s += __shfl_xor(s, o, 64);
    __shared__ int ws[4];
    if ((t & 63) == 0) ws[t >> 6] = s;
    __syncthreads();
    if (t == 0) bsum[blockIdx.x] = ws[0] + ws[1] + ws[2] + ws[3];
}

__global__ void scan_tops(int* __restrict__ bsum, int* __restrict__ offs_n, int nb) {
    const int lane = threadIdx.x & 63;
    int v = (lane < nb) ? bsum[lane] : 0;
    int incl = v;
#pragma unroll
    for (int o = 1; o < 64; o <<= 1) {
        int u = __shfl_up(incl, o, 64);
        if (lane >= o) incl += u;
    }
    if (lane < nb) bsum[lane] = incl - v;
    if (lane == 63) offs_n[0] = incl;
}

__global__ __launch_bounds__(256) void scan_add(const int* __restrict__ deg,
                                                const int* __restrict__ bsum,
                                                int* __restrict__ offs, int n) {
    const int t = threadIdx.x;
    const int i0 = blockIdx.x * 1024 + t * 4;
    int loc[4];
    int s = 0;
#pragma unroll
    for (int k = 0; k < 4; ++k) { int i = i0 + k; loc[k] = (i < n) ? deg[i] + 1 : 0; s += loc[k]; }
    int incl = s;
#pragma unroll
    for (int o = 1; o < 64; o <<= 1) {
        int u = __shfl_up(incl, o, 64);
        if ((t & 63) >= o) incl += u;
    }
    __shared__ int wsum[4];
    const int w = t >> 6;
    if ((t & 63) == 63) wsum[w] = incl;
    __syncthreads();
    int wbase = 0;
#pragma unroll
    for (int k = 0; k < 4; ++k) if (k < w) wbase += wsum[k];
    int base = bsum[blockIdx.x] + wbase + (incl - s);
#pragma unroll
    for (int k = 0; k < 4; ++k) { int i = i0 + k; if (i < n) offs[i] = base; base += loc[k]; }
}

__global__ void scatter_edges(const int* __restrict__ ei, const int* __restrict__ offs,
                              int* __restrict__ cur, int* __restrict__ csr, int E, int ET) {
    int e = blockIdx.x * blockDim.x + threadIdx.x;
    if (e >= ET) return;
    int s, d;
    if (e < E) { s = ei[e]; d = ei[E + e]; } else { s = d = e - E; }
    int pos = atomicAdd(&cur[d], 1);
    csr[offs[d] + pos] = s;
}

// ---------------- GEMM + fused attention logits ----------------
// block: 64 rows x 128 cols; thread (rg=tid>>4, cg=tid&15): 4 rows x
// cols [cg*4, cg*4+4) u [64+cg*4, 64+cg*4+4). W staged in LDS.
// Outputs: Yb (bf16x2 packed) + as_/ad_ (f32 per-node-per-head logits,
// LDS-reduced in the epilogue). No f32 Y.
#define GETK(v, kk) ((kk) == 0 ? (v).x : (kk) == 1 ? (v).y : (kk) == 2 ? (v).z : (v).w)

__device__ inline unsigned short f2bf(float x) {
    union { float f; unsigned int u; } v; v.f = x;
    unsigned int b = v.u + 0x7fffu + ((v.u >> 16) & 1u);  // round-nearest-even
    return (unsigned short)(b >> 16);
}
__device__ inline unsigned int pack2bf(float a, float b) {
    return (unsigned int)f2bf(a) | ((unsigned int)f2bf(b) << 16);
}

template <int H>
__global__ __launch_bounds__(256) void gemm_att(const float* __restrict__ X,
                                                const float* __restrict__ W,
                                                unsigned int* __restrict__ Yb,
                                                const float* __restrict__ att_s,
                                                const float* __restrict__ att_d,
                                                float* __restrict__ as_,
                                                float* __restrict__ ad_, int n) {
    __shared__ float Ws[128 * 128];
    __shared__ float red[64][H][2];
    {
        const float4* W4 = (const float4*)W;
        float4* S4 = (float4*)Ws;
#pragma unroll
        for (int i = 0; i < 16; ++i) S4[threadIdx.x + 256 * i] = W4[threadIdx.x + 256 * i];
        float* rf = (float*)red;
        for (int i = threadIdx.x; i < 64 * H * 2; i += 256) rf[i] = 0.f;
    }
    __syncthreads();
    const int cg = threadIdx.x & 15;
    const int rg = threadIdx.x >> 4;
    const int r0 = blockIdx.x * 64 + rg * 4;
    const int c0 = cg * 4, c1 = 64 + cg * 4;
    float acc[4][8] = {};
    const int nr = min(4, n - r0);  // may be <= 0; no early return (barriers!)

    if (nr == 4) {
        const float4* x0 = (const float4*)(X + (size_t)(r0 + 0) * 128);
        const float4* x1 = (const float4*)(X + (size_t)(r0 + 1) * 128);
        const float4* x2 = (const float4*)(X + (size_t)(r0 + 2) * 128);
        const float4* x3 = (const float4*)(X + (size_t)(r0 + 3) * 128);
#pragma unroll 2
        for (int k4 = 0; k4 < 32; ++k4) {
            float4 a0 = x0[k4], a1 = x1[k4], a2 = x2[k4], a3 = x3[k4];
#pragma unroll
            for (int kk = 0; kk < 4; ++kk) {
                const float* wr = &Ws[(k4 * 4 + kk) * 128];
                float4 w0 = *(const float4*)(wr + c0);
                float4 w1 = *(const float4*)(wr + c1);
                float v;
                v = GETK(a0, kk);
                acc[0][0] = fmaf(v, w0.x, acc[0][0]); acc[0][1] = fmaf(v, w0.y, acc[0][1]);
                acc[0][2] = fmaf(v, w0.z, acc[0][2]); acc[0][3] = fmaf(v, w0.w, acc[0][3]);
                acc[0][4] = fmaf(v, w1.x, acc[0][4]); acc[0][5] = fmaf(v, w1.y, acc[0][5]);
                acc[0][6] = fmaf(v, w1.z, acc[0][6]); acc[0][7] = fmaf(v, w1.w, acc[0][7]);
                v = GETK(a1, kk);
                acc[1][0] = fmaf(v, w0.x, acc[1][0]); acc[1][1] = fmaf(v, w0.y, acc[1][1]);
                acc[1][2] = fmaf(v, w0.z, acc[1][2]); acc[1][3] = fmaf(v, w0.w, acc[1][3]);
                acc[1][4] = fmaf(v, w1.x, acc[1][4]); acc[1][5] = fmaf(v, w1.y, acc[1][5]);
                acc[1][6] = fmaf(v, w1.z, acc[1][6]); acc[1][7] = fmaf(v, w1.w, acc[1][7]);
                v = GETK(a2, kk);
                acc[2][0] = fmaf(v, w0.x, acc[2][0]); acc[2][1] = fmaf(v, w0.y, acc[2][1]);
                acc[2][2] = fmaf(v, w0.z, acc[2][2]); acc[2][3] = fmaf(v, w0.w, acc[2][3]);
                acc[2][4] = fmaf(v, w1.x, acc[2][4]); acc[2][5] = fmaf(v, w1.y, acc[2][5]);
                acc[2][6] = fmaf(v, w1.z, acc[2][6]); acc[2][7] = fmaf(v, w1.w, acc[2][7]);
                v = GETK(a3, kk);
                acc[3][0] = fmaf(v, w0.x, acc[3][0]); acc[3][1] = fmaf(v, w0.y, acc[3][1]);
                acc[3][2] = fmaf(v, w0.z, acc[3][2]); acc[3][3] = fmaf(v, w0.w, acc[3][3]);
                acc[3][4] = fmaf(v, w1.x, acc[3][4]); acc[3][5] = fmaf(v, w1.y, acc[3][5]);
                acc[3][6] = fmaf(v, w1.z, acc[3][6]); acc[3][7] = fmaf(v, w1.w, acc[3][7]);
            }
        }
    } else if (nr > 0) {
        for (int k = 0; k < 128; ++k) {
            const float* wr = &Ws[k * 128];
            for (int r = 0; r < nr; ++r) {
                float v = X[(size_t)(r0 + r) * 128 + k];
#pragma unroll
                for (int c = 0; c < 4; ++c) {
                    acc[r][c]     = fmaf(v, wr[c0 + c], acc[r][c]);
                    acc[r][4 + c] = fmaf(v, wr[c1 + c], acc[r][4 + c]);
                }
            }
        }
    }

    if (nr > 0) {
        const float4 sv0 = *(const float4*)(att_s + c0);
        const float4 dv0 = *(const float4*)(att_d + c0);
        const float4 sv1 = *(const float4*)(att_s + c1);
        const float4 dv1 = *(const float4*)(att_d + c1);
        for (int r = 0; r < nr; ++r) {
            unsigned int* br = Yb + (size_t)(r0 + r) * 64;
            uint2 p0 = {pack2bf(acc[r][0], acc[r][1]), pack2bf(acc[r][2], acc[r][3])};
            uint2 p1 = {pack2bf(acc[r][4], acc[r][5]), pack2bf(acc[r][6], acc[r][7])};
            *(uint2*)(br + cg * 2) = p0;
            *(uint2*)(br + 32 + cg * 2) = p1;
            float ps0 = acc[r][0] * sv0.x + acc[r][1] * sv0.y + acc[r][2] * sv0.z + acc[r][3] * sv0.w;
            float pd0 = acc[r][0] * dv0.x + acc[r][1] * dv0.y + acc[r][2] * dv0.z + acc[r][3] * dv0.w;
            float ps1 = acc[r][4] * sv1.x + acc[r][5] * sv1.y + acc[r][6] * sv1.z + acc[r][7] * sv1.w;
            float pd1 = acc[r][4] * dv1.x + acc[r][5] * dv1.y + acc[r][6] * dv1.z + acc[r][7] * dv1.w;
            const int rl = rg * 4 + r;
            if constexpr (H == 4) {
                atomicAdd(&red[rl][c0 >> 5][0], ps0); atomicAdd(&red[rl][c0 >> 5][1], pd0);
                atomicAdd(&red[rl][c1 >> 5][0], ps1); atomicAdd(&red[rl][c1 >> 5][1], pd1);
            } else {
                atomicAdd(&red[rl][0][0], ps0 + ps1); atomicAdd(&red[rl][0][1], pd0 + pd1);
            }
        }
    }
    __syncthreads();
    for (int i = threadIdx.x; i < 64 * H; i += 256) {
        const int rl = i / H, h = i - rl * H;
        const int node = blockIdx.x * 64 + rl;
        if (node < n) {
            as_[(size_t)node * H + h] = red[rl][h][0];
            ad_[(size_t)node * H + h] = red[rl][h][1];
        }
    }
}

// ---------------- gather v4: lane-parallel softmax, broadcast inner loop ----
// one wave per dst node; lane owns channels {2*lane, 2*lane+1}.
// phase A: lane j computes p (all heads) for edge j -> per-wave LDS {p4, s}.
// phase B: per edge: ds_read(p, s) broadcast + bf16x2 h load + 2 fma.
// denom: lane-local accumulation, single butterfly at the end.
template <int H, bool DO_ELU>
__global__ __launch_bounds__(256) void gat_gather4(
    const int* __restrict__ csr, const int* __restrict__ offs,
    const float* __restrict__ as_, const float* __restrict__ ad_,
    const unsigned int* __restrict__ hb,  // bf16x2 rows, 64 uints/node
    const float* __restrict__ bias, float* __restrict__ out, int n)
{
    constexpr int PW = (H == 4) ? 8 : 2;  // LDS words per edge {p[H], s}
    __shared__ float plds[4][64][PW];
    const int node = (int)(((size_t)blockIdx.x * blockDim.x + threadIdx.x) >> 6);
    if (node >= n) return;  // whole waves exit; kernel has no block barriers
    const int lane = threadIdx.x & 63;
    const int w = threadIdx.x >> 6;
    const int hd = lane >> 4;
    const int start = offs[node];
    const int deg = offs[node + 1] - start;  // >= 1 (self-loop)

    float adx = 0.f, ady = 0.f, adz = 0.f, adw = 0.f;
    if constexpr (H == 4) {
        const float4 adv = *(const float4*)(ad_ + (size_t)node * 4);
        adx = adv.x; ady = adv.y; adz = adv.z; adw = adv.w;
    } else {
        adx = ad_[node];
    }

    float2 acc = {0.f, 0.f};
    float dsx = 0.f, dsy = 0.f, dsz = 0.f, dsw = 0.f;  // lane-local denom parts

    for (int base = 0; base < deg; base += 64) {
        const int cnt = min(deg - base, 64);
        // ---- phase A: lane j -> edge j ----
        if (lane < cnt) {
            const int s = csr[start + base + lane];
            const float sf = __int_as_float(s);
            if constexpr (H == 4) {
                const float4 a = ((const float4*)as_)[s];
                float e0 = a.x + adx; e0 = fmaxf(e0, NEG_SLOPE * e0);
                float e1 = a.y + ady; e1 = fmaxf(e1, NEG_SLOPE * e1);
                float e2 = a.z + adz; e2 = fmaxf(e2, NEG_SLOPE * e2);
                float e3 = a.w + adw; e3 = fmaxf(e3, NEG_SLOPE * e3);
                float4 p4 = {__expf(e0), __expf(e1), __expf(e2), __expf(e3)};
                dsx += p4.x; dsy += p4.y; dsz += p4.z; dsw += p4.w;
                *(float4*)&plds[w][lane][0] = p4;
                float4 s4 = {sf, sf, sf, sf};
                *(float4*)&plds[w][lane][4] = s4;
            } else {
                float e0 = as_[s] + adx; e0 = fmaxf(e0, NEG_SLOPE * e0);
                float p = __expf(e0);
                dsx += p;
                float2 ps = {p, sf};
                *(float2*)&plds[w][lane][0] = ps;
            }
        }
        // drain LDS writes; same-wave DS ops are in-order, so reads below see them
        asm volatile("s_waitcnt lgkmcnt(0)" ::: "memory");
        __builtin_amdgcn_sched_barrier(0);

        // ---- phase B: depth-3 pipelined broadcast loop ----
        float pA = 0.f, pB = 0.f, pC = 0.f;
        unsigned int hA = 0, hB = 0, hC = 0;
#define PRELB(S, T)                                                             \
    if ((T) < cnt) {                                                            \
        const float* q = &plds[w][(T)][0];                                      \
        int _s;                                                                 \
        if constexpr (H == 4) { p##S = q[hd]; _s = __float_as_int(q[4 + hd]); } \
        else                  { p##S = q[0];  _s = __float_as_int(q[1]); }      \
        h##S = hb[(size_t)(unsigned)_s * 64 + lane];                            \
    }
#define CONSB(S)                                                                \
    {                                                                           \
        acc.x = fmaf(p##S, __uint_as_float(h##S << 16), acc.x);                 \
        acc.y = fmaf(p##S, __uint_as_float(h##S & 0xffff0000u), acc.y);         \
    }
        PRELB(A, 0)
        PRELB(B, 1)
        PRELB(C, 2)
        int t = 0;
        for (; t + 3 <= cnt; t += 3) {
            CONSB(A) PRELB(A, t + 3)
            CONSB(B) PRELB(B, t + 4)
            CONSB(C) PRELB(C, t + 5)
        }
        if (t < cnt)     CONSB(A)
        if (t + 1 < cnt) CONSB(B)
        if (t + 2 < cnt) CONSB(C)
#undef PRELB
#undef CONSB
    }

    // ---- final denom: one butterfly over the lane-local partials ----
#pragma unroll
    for (int o = 1; o < 64; o <<= 1) {
        dsx += __shfl_xor(dsx, o, 64);
        if constexpr (H == 4) {
            dsy += __shfl_xor(dsy, o, 64);
            dsz += __shfl_xor(dsz, o, 64);
            dsw += __shfl_xor(dsw, o, 64);
        }
    }
    float ds;
    if constexpr (H == 4) ds = hd == 0 ? dsx : hd == 1 ? dsy : hd == 2 ? dsz : dsw;
    else                  ds = dsx;

    const float2 bv = ((const float2*)bias)[lane];
    const float inv = 1.f / (ds + 1e-16f);
    float v0 = acc.x * inv + bv.x;
    float v1 = acc.y * inv + bv.y;
    if constexpr (DO_ELU) {
        v0 = v0 > 0.f ? v0 : __expf(v0) - 1.f;
        v1 = v1 > 0.f ? v1 : __expf(v1) - 1.f;
    }
    ((float2*)out)[(size_t)node * 64 + lane] = {v0, v1};
}

extern "C" void kernel_launch(void* const* d_in, const int* in_sizes, int n_in,
                              void* d_out, int out_size, void* d_ws, size_t ws_size,
                              hipStream_t stream) {
    const float* x        = (const float*)d_in[0];
    const int*   ei       = (const int*)d_in[1];
    const float* W1       = (const float*)d_in[2];
    const float* att_src1 = (const float*)d_in[3];
    const float* att_dst1 = (const float*)d_in[4];
    const float* b1       = (const float*)d_in[5];
    const float* W2       = (const float*)d_in[6];
    const float* att_src2 = (const float*)d_in[7];
    const float* att_dst2 = (const float*)d_in[8];
    const float* b2       = (const float*)d_in[9];

    const int n  = in_sizes[0] / 128;
    const int E  = in_sizes[1] / 2;
    const int ET = E + n;
    const int nb = (n + 1023) / 1024;  // <= 64 for n <= 65536

    float*        ws   = (float*)d_ws;
    float*        B    = ws;                                   // [n*128] layer-1 out
    unsigned int* Hbf  = (unsigned int*)(B + (size_t)n * 128); // [n*64] bf16 h
    float*        as_  = (float*)(Hbf + (size_t)n * 64);       // [n*4]
    float*        ad_  = as_ + (size_t)n * 4;                  // [n*4]
    int*          deg  = (int*)(ad_ + (size_t)n * 4);          // [n]
    int*          cur  = deg + n;                              // [n]
    int*          offs = cur + n;                              // [n+1]
    int*          bsum = offs + n + 1;                         // [64]
    int*          csr  = bsum + 64;                            // [ET]

    float* outf = (float*)d_out;

    // ---------------- CSR build ----------------
    hipMemsetAsync(deg, 0, (size_t)2 * n * sizeof(int), stream);  // deg + cur
    deg_hist<<<(E + 255) / 256, 256, 0, stream>>>(ei, deg, E);
    scan_part<<<nb, 256, 0, stream>>>(deg, bsum, n);
    scan_tops<<<1, 64, 0, stream>>>(bsum, offs + n, nb);
    scan_add<<<nb, 256, 0, stream>>>(deg, bsum, offs, n);
    scatter_edges<<<(ET + 255) / 256, 256, 0, stream>>>(ei, offs, cur, csr, E, ET);

    // ---------------- layer 1 ----------------
    gemm_att<4><<<(n + 63) / 64, 256, 0, stream>>>(x, W1, Hbf, att_src1, att_dst1, as_, ad_, n);
    gat_gather4<4, true><<<((size_t)n * 64 + 255) / 256, 256, 0, stream>>>(
        csr, offs, as_, ad_, Hbf, b1, B, n);

    // ---------------- layer 2 ----------------
    gemm_att<1><<<(n + 63) / 64, 256, 0, stream>>>(B, W2, Hbf, att_src2, att_dst2, as_, ad_, n);
    gat_gather4<1, false><<<((size_t)n * 64 + 255) / 256, 256, 0, stream>>>(
        csr, offs, as_, ad_, Hbf, b2, outf, n);
}